// Round 1
// baseline (608.696 us; speedup 1.0000x reference)
//
#include <hip/hip_runtime.h>

// Problem constants (from reference)
#define Bdim   4
#define Tdim   1024
#define NLAB   64
#define Cdim   256
#define Ddim   512
#define HALF   256        // VALUE_DIM/2
#define BT     (Bdim*Tdim)

// Grid: 64 labels x 4 d-chunks (64 d's each) = 256 blocks, 256 threads.
__global__ __launch_bounds__(256) void vb_kernel(
    const int*   __restrict__ indices,   // [B*T]
    const float* __restrict__ scores,    // [B*T]
    const float* __restrict__ W,         // [NLAB, Ddim, Cdim]
    const int*   __restrict__ label,     // [B*T]
    const int*   __restrict__ index_p,   // [1]
    const float* __restrict__ weight,    // [VALUE_SIZE, Ddim]
    float*       __restrict__ out)       // [B, Cdim]
{
    const int l     = blockIdx.x & 63;
    const int chunk = blockIdx.x >> 6;       // 0..3 -> d in [chunk*64, chunk*64+64)
    const int tid   = threadIdx.x;
    const int half  = (index_p[0] == 1) ? HALF : 0;
    const int dglob = half + chunk * 64;     // global d offset for this block

    __shared__ int   s_list[BT];             // 16 KB: matching flat bt indices
    __shared__ int   s_count;
    __shared__ float A_part[4][Bdim][64];    // 4 KB: per-slot accumulators (race-free)
    __shared__ float A_red[Bdim][64];        // 1 KB
    __shared__ float P[4][Bdim][Cdim];       // 16 KB: stage-2 partials across d_base

    // ---- init LDS ----
    if (tid == 0) s_count = 0;
    {
        float* ap = &A_part[0][0][0];
        #pragma unroll
        for (int i = 0; i < 4; ++i) ap[tid + 256 * i] = 0.0f;
    }
    __syncthreads();

    // ---- compact (b,t) entries with label == l ----
    #pragma unroll
    for (int i = 0; i < BT / 256; ++i) {
        int bt = i * 256 + tid;
        if (label[bt] == l) {
            int pos = atomicAdd(&s_count, 1);
            s_list[pos] = bt;
        }
    }
    __syncthreads();
    const int count = s_count;

    // ---- stage 1: A[b,d] = sum over matches of score * weight[idx, dglob+d] ----
    const int slot = tid >> 6;    // 0..3, one match per 64-lane group
    const int dl   = tid & 63;    // local d
    for (int m = slot; m < count; m += 4) {
        int   bt  = s_list[m];
        int   b   = bt >> 10;     // T = 1024
        float s   = scores[bt];
        int   idx = indices[bt];
        float w   = weight[(size_t)idx * Ddim + dglob + dl];
        A_part[slot][b][dl] += s * w;
    }
    __syncthreads();

    // reduce the 4 slots: threads = b(4) x d(64)
    {
        int b = tid >> 6, d = tid & 63;
        A_red[b][d] = A_part[0][b][d] + A_part[1][b][d]
                    + A_part[2][b][d] + A_part[3][b][d];
    }
    __syncthreads();

    // ---- stage 2: out[b,c] += sum_d A[b,d] * W[l, dglob+d, c] ----
    const int c4     = (tid & 63) * 4;   // 4 consecutive c per thread
    const int d_base = tid >> 6;         // 0..3 (wave-uniform)

    float4 acc[Bdim];
    #pragma unroll
    for (int b = 0; b < Bdim; ++b) acc[b] = make_float4(0.f, 0.f, 0.f, 0.f);

    #pragma unroll 4
    for (int dd = 0; dd < 16; ++dd) {
        int dloc = dd * 4 + d_base;      // 0..63
        const float4 wv = *(const float4*)(
            W + ((size_t)(l * Ddim + dglob + dloc) * Cdim + c4));
        #pragma unroll
        for (int b = 0; b < Bdim; ++b) {
            float a = A_red[b][dloc];    // broadcast within wave
            acc[b].x += a * wv.x;
            acc[b].y += a * wv.y;
            acc[b].z += a * wv.z;
            acc[b].w += a * wv.w;
        }
    }

    // write partials, reduce over d_base groups
    #pragma unroll
    for (int b = 0; b < Bdim; ++b)
        *(float4*)&P[d_base][b][c4] = acc[b];
    __syncthreads();

    {
        int c = tid;  // 0..255
        #pragma unroll
        for (int b = 0; b < Bdim; ++b) {
            float s = P[0][b][c] + P[1][b][c] + P[2][b][c] + P[3][b][c];
            atomicAdd(&out[b * Cdim + c], s);
        }
    }
}

extern "C" void kernel_launch(void* const* d_in, const int* in_sizes, int n_in,
                              void* d_out, int out_size, void* d_ws, size_t ws_size,
                              hipStream_t stream) {
    const int*   indices = (const int*)  d_in[0];
    const float* scores  = (const float*)d_in[1];
    const float* W       = (const float*)d_in[2];
    const int*   label   = (const int*)  d_in[3];
    const int*   index_p = (const int*)  d_in[4];
    const float* weight  = (const float*)d_in[5];
    float*       out     = (float*)d_out;

    hipMemsetAsync(out, 0, (size_t)out_size * sizeof(float), stream);
    vb_kernel<<<dim3(256), dim3(256), 0, stream>>>(
        indices, scores, W, label, index_p, weight, out);
}

// Round 2
// 604.946 us; speedup vs baseline: 1.0062x; 1.0062x over previous
//
#include <hip/hip_runtime.h>

// Problem constants (from reference)
#define Bdim   4
#define Tdim   1024
#define NLAB   64
#define Cdim   256
#define Ddim   512
#define HALF   256        // VALUE_DIM/2
#define BT     (Bdim*Tdim)

// Grid: 64 labels x 4 d-chunks (64 d's each) = 256 blocks, 256 threads (4 waves).
__global__ __launch_bounds__(256) void vb_kernel(
    const int*   __restrict__ indices,   // [B*T]
    const float* __restrict__ scores,    // [B*T]
    const float* __restrict__ W,         // [NLAB, Ddim, Cdim]
    const int*   __restrict__ label,     // [B*T]
    const int*   __restrict__ index_p,   // [1]
    const float* __restrict__ weight,    // [VALUE_SIZE, Ddim]
    float*       __restrict__ out)       // [B, Cdim]
{
    const int l     = blockIdx.x & 63;
    const int chunk = blockIdx.x >> 6;       // 0..3 -> d in [chunk*64, chunk*64+64)
    const int tid   = threadIdx.x;
    const int lane  = tid & 63;
    const int wave  = tid >> 6;
    const int half  = (index_p[0] == 1) ? HALF : 0;
    const int dglob = half + chunk * 64;     // global d offset for this block

    __shared__ int   s_list[BT];             // 16 KB: matching flat bt indices
    __shared__ int   s_count;
    __shared__ float A_part[16][Bdim][64];   // 16 KB: per-slot partials (race-free)
    __shared__ float A_red[Bdim][64];        // 1 KB
    __shared__ float P[4][Bdim][Cdim];       // 16 KB: stage-2 partials across waves

    if (tid == 0) s_count = 0;
    __syncthreads();

    // ---- compact (b,t) with label == l : wave-aggregated (ballot) push ----
    #pragma unroll
    for (int i = 0; i < 4; ++i) {
        int4 lv = ((const int4*)label)[i * 256 + tid];   // bt = (i*256+tid)*4 + j
        int bt0 = (i * 256 + tid) * 4;
        int lv_arr[4] = {lv.x, lv.y, lv.z, lv.w};
        #pragma unroll
        for (int j = 0; j < 4; ++j) {
            bool m = (lv_arr[j] == l);
            unsigned long long mask = __ballot(m);
            int base_s = 0;
            if (lane == 0 && mask)
                base_s = atomicAdd(&s_count, __popcll(mask));
            base_s = __shfl(base_s, 0, 64);
            if (m) {
                int pre = __popcll(mask & ((1ull << lane) - 1ull));
                s_list[base_s + pre] = bt0 + j;
            }
        }
    }
    __syncthreads();
    const int count = s_count;

    // ---- stage 1: A[b,d] = sum over matches of score * weight[idx, dglob+d] ----
    // 16 slots = wave(4) x q(4); each slot's 16 lanes load one match row as float4.
    const int q    = lane >> 4;          // 0..3
    const int cl   = lane & 15;          // 0..15 -> d = cl*4..cl*4+3
    const int slot = wave * 4 + q;       // 0..15

    float4 acc0 = {0,0,0,0}, acc1 = {0,0,0,0}, acc2 = {0,0,0,0}, acc3 = {0,0,0,0};
    for (int m = slot; m < count; m += 16) {
        int   bt  = s_list[m];
        int   b   = bt >> 10;            // T = 1024
        float s   = scores[bt];
        int   idx = indices[bt];
        const float4 w = *(const float4*)(weight + (size_t)idx * Ddim + dglob + cl * 4);
        float s0 = (b == 0) ? s : 0.0f;
        float s1 = (b == 1) ? s : 0.0f;
        float s2 = (b == 2) ? s : 0.0f;
        float s3 = (b == 3) ? s : 0.0f;
        acc0.x += s0 * w.x; acc0.y += s0 * w.y; acc0.z += s0 * w.z; acc0.w += s0 * w.w;
        acc1.x += s1 * w.x; acc1.y += s1 * w.y; acc1.z += s1 * w.z; acc1.w += s1 * w.w;
        acc2.x += s2 * w.x; acc2.y += s2 * w.y; acc2.z += s2 * w.z; acc2.w += s2 * w.w;
        acc3.x += s3 * w.x; acc3.y += s3 * w.y; acc3.z += s3 * w.z; acc3.w += s3 * w.w;
    }
    *(float4*)&A_part[slot][0][cl * 4] = acc0;
    *(float4*)&A_part[slot][1][cl * 4] = acc1;
    *(float4*)&A_part[slot][2][cl * 4] = acc2;
    *(float4*)&A_part[slot][3][cl * 4] = acc3;
    __syncthreads();

    // reduce 16 slots: threads = b(4) x d(64)
    {
        int b = tid >> 6, d = tid & 63;
        float s = 0.0f;
        #pragma unroll
        for (int k = 0; k < 16; ++k) s += A_part[k][b][d];
        A_red[b][d] = s;
    }
    __syncthreads();

    // ---- stage 2: out[b,c] += sum_d A[b,d] * W[l, dglob+d, c] ----
    const int c4 = lane * 4;             // 4 consecutive c per thread

    float4 acc[Bdim];
    #pragma unroll
    for (int b = 0; b < Bdim; ++b) acc[b] = make_float4(0.f, 0.f, 0.f, 0.f);

    #pragma unroll
    for (int dd = 0; dd < 16; ++dd) {
        int dloc = dd * 4 + wave;        // 0..63, wave-uniform
        const float4 wv = *(const float4*)(
            W + ((size_t)(l * Ddim + dglob + dloc) * Cdim + c4));
        #pragma unroll
        for (int b = 0; b < Bdim; ++b) {
            float a = A_red[b][dloc];
            acc[b].x += a * wv.x;
            acc[b].y += a * wv.y;
            acc[b].z += a * wv.z;
            acc[b].w += a * wv.w;
        }
    }

    #pragma unroll
    for (int b = 0; b < Bdim; ++b)
        *(float4*)&P[wave][b][c4] = acc[b];
    __syncthreads();

    {
        int c = tid;  // 0..255
        #pragma unroll
        for (int b = 0; b < Bdim; ++b) {
            float s = P[0][b][c] + P[1][b][c] + P[2][b][c] + P[3][b][c];
            atomicAdd(&out[b * Cdim + c], s);
        }
    }
}

extern "C" void kernel_launch(void* const* d_in, const int* in_sizes, int n_in,
                              void* d_out, int out_size, void* d_ws, size_t ws_size,
                              hipStream_t stream) {
    const int*   indices = (const int*)  d_in[0];
    const float* scores  = (const float*)d_in[1];
    const float* W       = (const float*)d_in[2];
    const int*   label   = (const int*)  d_in[3];
    const int*   index_p = (const int*)  d_in[4];
    const float* weight  = (const float*)d_in[5];
    float*       out     = (float*)d_out;

    hipMemsetAsync(out, 0, (size_t)out_size * sizeof(float), stream);
    vb_kernel<<<dim3(256), dim3(256), 0, stream>>>(
        indices, scores, W, label, index_p, weight, out);
}